// Round 1
// baseline (196.659 us; speedup 1.0000x reference)
//
#include <hip/hip_runtime.h>
#include <stdint.h>
#include <stddef.h>

// ---------- types ----------
typedef short s16x8 __attribute__((ext_vector_type(8)));   // 8 bf16 (bit pattern in shorts)
typedef float f32x4 __attribute__((ext_vector_type(4)));

#define MFMA16(a, b, c) __builtin_amdgcn_mfma_f32_16x16x32_bf16((a), (b), (c), 0, 0, 0)

// fp32 -> bf16 (RNE)
__device__ __forceinline__ unsigned short f2bf(float f) {
  union { float f; uint32_t u; } v; v.f = f;
  uint32_t u = v.u;
  return (unsigned short)((u + 0x7FFFu + ((u >> 16) & 1u)) >> 16);
}

// async global->LDS, 16B per lane. LDS dest must be wave-uniform base + lane*16.
__device__ __forceinline__ void load_lds16(const void* gsrc, void* ldst) {
  void* gp = const_cast<void*>(gsrc);
  __builtin_amdgcn_global_load_lds(
      (__attribute__((address_space(1))) void*)gp,
      (__attribute__((address_space(3))) void*)ldst, 16, 0, 0);
}

// ---------- problem constants ----------
#define B_    2
#define L_    2048
#define DIM_  1024
#define NH_   16
#define HD_   64
#define MTOT  (B_ * L_)       // 4096
#define SCALE_ 0.125f         // 64^-0.5

// ---------- fp32 -> bf16 convert (vectorized) ----------
__global__ void cvt_f32_bf16(const float* __restrict__ in, unsigned short* __restrict__ out, int n4) {
  int i = blockIdx.x * blockDim.x + threadIdx.x;
  if (i < n4) {
    float4 v = ((const float4*)in)[i];
    uint2 r;
    r.x = (uint32_t)f2bf(v.x) | ((uint32_t)f2bf(v.y) << 16);
    r.y = (uint32_t)f2bf(v.z) | ((uint32_t)f2bf(v.w) << 16);
    ((uint2*)out)[i] = r;
  }
}

// ---------- GEMM C[m][n] = sum_k A[m][k] * Bw[n][k]  (both bf16, K-major) ----------
// 128x128 tile, BK=32, 4 waves (2x2 of 64x64), 16x16x32 MFMA.
// EPI 0: scatter to Q/K [b,h,l,d] and V^T [b,h,d,l] (bf16).
// EPI 1: fp32 out + bias.
template <int EPI>
__global__ void __launch_bounds__(256)
gemm_bt(const unsigned short* __restrict__ A,
        const unsigned short* __restrict__ Bw,
        int M, int N, int K,
        unsigned short* __restrict__ Qb,
        unsigned short* __restrict__ Kb,
        unsigned short* __restrict__ Vt,
        float* __restrict__ Cout,
        const float* __restrict__ bias) {
  __shared__ __attribute__((aligned(16))) unsigned short Al[128 * 32];
  __shared__ __attribute__((aligned(16))) unsigned short Bl[128 * 32];
  const int tid  = threadIdx.x;
  const int lane = tid & 63, wv = tid >> 6;
  const int g = lane >> 4, lr = lane & 15;
  const int wr = wv >> 1, wc = wv & 1;
  const int m0 = blockIdx.x * 128, n0 = blockIdx.y * 128;

  f32x4 acc[4][4];
  const f32x4 zero = {0.f, 0.f, 0.f, 0.f};
#pragma unroll
  for (int i = 0; i < 4; i++)
#pragma unroll
    for (int j = 0; j < 4; j++) acc[i][j] = zero;

  for (int k0 = 0; k0 < K; k0 += 32) {
    // stage A,B tiles: 512 x 16B chunks each; chunk c <-> (row=c>>2, kc=c&3).
    // LDS is linear; source chunk pre-swizzled by s(row) = (row^(row>>2))&3.
#pragma unroll
    for (int pass = 0; pass < 2; ++pass) {
      int c   = pass * 256 + wv * 64 + lane;
      int row = c >> 2, kc = c & 3;
      int ks  = (kc ^ ((row ^ (row >> 2)) & 3)) * 8;
      load_lds16(A  + (size_t)(m0 + row) * K + k0 + ks, (char*)Al + c * 16);
      load_lds16(Bw + (size_t)(n0 + row) * K + k0 + ks, (char*)Bl + c * 16);
    }
    __syncthreads();

    s16x8 af[4], bf[4];
#pragma unroll
    for (int mi = 0; mi < 4; mi++) {
      int row = wr * 64 + mi * 16 + lr;
      int ch  = g ^ ((row ^ (row >> 2)) & 3);
      af[mi]  = *(const s16x8*)((const char*)Al + row * 64 + ch * 16);
    }
#pragma unroll
    for (int ni = 0; ni < 4; ni++) {
      int row = wc * 64 + ni * 16 + lr;
      int ch  = g ^ ((row ^ (row >> 2)) & 3);
      bf[ni]  = *(const s16x8*)((const char*)Bl + row * 64 + ch * 16);
    }
#pragma unroll
    for (int mi = 0; mi < 4; mi++)
#pragma unroll
      for (int ni = 0; ni < 4; ni++)
        acc[mi][ni] = MFMA16(af[mi], bf[ni], acc[mi][ni]);
    __syncthreads();
  }

  // epilogue: D layout col = lane&15, row = (lane>>4)*4 + j
  if (EPI == 0) {
#pragma unroll
    for (int mi = 0; mi < 4; mi++)
#pragma unroll
      for (int ni = 0; ni < 4; ni++) {
        int ncol = n0 + wc * 64 + ni * 16 + lr;
        int s = ncol >> 10;           // 0=Q 1=K 2=V (uniform per block)
        int h = (ncol >> 6) & 15;
        int d = ncol & 63;
#pragma unroll
        for (int j = 0; j < 4; j++) {
          int m = m0 + wr * 64 + mi * 16 + g * 4 + j;
          int b = m >> 11, l = m & 2047;
          unsigned short v = f2bf(acc[mi][ni][j]);
          size_t bh = (size_t)(b * NH_ + h);
          if (s == 0)      Qb[(bh * L_ + l) * HD_ + d] = v;
          else if (s == 1) Kb[(bh * L_ + l) * HD_ + d] = v;
          else             Vt[(bh * HD_ + d) * L_ + l] = v;   // transposed
        }
      }
  } else {
#pragma unroll
    for (int mi = 0; mi < 4; mi++)
#pragma unroll
      for (int ni = 0; ni < 4; ni++) {
        int ncol = n0 + wc * 64 + ni * 16 + lr;
        float bv = bias[ncol];
#pragma unroll
        for (int j = 0; j < 4; j++) {
          int m = m0 + wr * 64 + mi * 16 + g * 4 + j;
          Cout[(size_t)m * N + ncol] = acc[mi][ni][j] + bv;
        }
      }
  }
}

// ---------- flash attention ----------
// grid: (L/64 q-tiles, B*H). 4 waves x 16 q-rows. KVBLK=64.
// Q,K: [b,h,l,d] bf16.  Vt: [b,h,d,l] bf16.  Out Ob: [b, l, h*64+d] bf16.
__global__ void __launch_bounds__(256)
attn_fwd(const unsigned short* __restrict__ Qb,
         const unsigned short* __restrict__ Kb,
         const unsigned short* __restrict__ Vt,
         unsigned short* __restrict__ Ob) {
  __shared__ __attribute__((aligned(16))) unsigned short Kl[64 * 64];   // [kv][d]
  __shared__ __attribute__((aligned(16))) unsigned short Vl[64 * 64];   // [d][kv]
  __shared__ __attribute__((aligned(16))) unsigned short Pl[4][16 * 64];// per-wave [q][kv]

  const int tid  = threadIdx.x;
  const int lane = tid & 63, wv = tid >> 6;
  const int g = lane >> 4, lr = lane & 15;
  const int qt = blockIdx.x, bh = blockIdx.y;

  const unsigned short* Qh = Qb + (size_t)bh * L_ * HD_;
  const unsigned short* Kh = Kb + (size_t)bh * L_ * HD_;
  const unsigned short* Vh = Vt + (size_t)bh * HD_ * L_;
  const int q0 = qt * 64 + wv * 16;

  // Q fragments: row = lr, k = kb*32 + g*8 + i (16B contiguous)
  s16x8 qf[2];
#pragma unroll
  for (int kb = 0; kb < 2; kb++)
    qf[kb] = *(const s16x8*)(Qh + (size_t)(q0 + lr) * HD_ + kb * 32 + g * 8);

  f32x4 o[4];  // o[dn]: rows q=g*4+j, cols d=dn*16+lr
  const f32x4 zero = {0.f, 0.f, 0.f, 0.f};
#pragma unroll
  for (int dn = 0; dn < 4; dn++) o[dn] = zero;
  float mrow[4], lrow[4];
#pragma unroll
  for (int j = 0; j < 4; j++) { mrow[j] = -1e30f; lrow[j] = 0.f; }

  for (int kv0 = 0; kv0 < L_; kv0 += 64) {
    // stage K tile [64][64] and V^T tile [64][64]; 512 chunks each, swizzle ^(row&7)
#pragma unroll
    for (int pass = 0; pass < 2; ++pass) {
      int c = pass * 256 + wv * 64 + lane;
      int row = c >> 3, cc = c & 7;
      int cs = (cc ^ (row & 7)) * 8;
      load_lds16(Kh + (size_t)(kv0 + row) * HD_ + cs, (char*)Kl + c * 16);
      load_lds16(Vh + (size_t)row * L_ + kv0 + cs,    (char*)Vl + c * 16);
    }
    __syncthreads();

    // S = Q K^T (rows q, cols kv), 4 col-subtiles
    f32x4 sv[4];
#pragma unroll
    for (int n = 0; n < 4; n++) {
      f32x4 z = zero;
#pragma unroll
      for (int kb = 0; kb < 2; kb++) {
        int row = n * 16 + lr;                      // kv row
        int ch  = ((kb << 2) | g) ^ (row & 7);
        s16x8 kf = *(const s16x8*)((const char*)Kl + row * 128 + ch * 16);
        z = MFMA16(qf[kb], kf, z);
      }
      sv[n] = z * SCALE_;
    }

    // online softmax; row q = g*4+j lives on the 16 lanes of group g
    float mnew[4], alpha[4], psum[4];
#pragma unroll
    for (int j = 0; j < 4; j++) {
      float t = fmaxf(fmaxf(sv[0][j], sv[1][j]), fmaxf(sv[2][j], sv[3][j]));
#pragma unroll
      for (int off = 1; off < 16; off <<= 1) t = fmaxf(t, __shfl_xor(t, off));
      mnew[j]  = fmaxf(mrow[j], t);
      alpha[j] = __expf(mrow[j] - mnew[j]);
      mrow[j]  = mnew[j];
      psum[j]  = 0.f;
    }
#pragma unroll
    for (int n = 0; n < 4; n++)
#pragma unroll
      for (int j = 0; j < 4; j++) {
        float p = __expf(sv[n][j] - mnew[j]);
        sv[n][j] = p;
        psum[j] += p;
      }
#pragma unroll
    for (int j = 0; j < 4; j++) {
#pragma unroll
      for (int off = 1; off < 16; off <<= 1) psum[j] += __shfl_xor(psum[j], off);
      lrow[j] = lrow[j] * alpha[j] + psum[j];
    }
#pragma unroll
    for (int dn = 0; dn < 4; dn++) {
      f32x4 t = o[dn];
      t[0] *= alpha[0]; t[1] *= alpha[1]; t[2] *= alpha[2]; t[3] *= alpha[3];
      o[dn] = t;
    }

    // P -> wave-private LDS (bf16), element-index swizzle kv ^= (q&7)<<3
#pragma unroll
    for (int n = 0; n < 4; n++)
#pragma unroll
      for (int j = 0; j < 4; j++) {
        int q   = g * 4 + j;
        int kvi = (n * 16 + lr) ^ ((q & 7) << 3);
        Pl[wv][q * 64 + kvi] = f2bf(sv[n][j]);
      }

    // PV: O += P V   (A=P rows q=lr; B=V^T rows d)
#pragma unroll
    for (int kb = 0; kb < 2; kb++) {
      int chp = ((kb << 2) | g) ^ (lr & 7);
      s16x8 pf = *(const s16x8*)((const char*)&Pl[wv][0] + lr * 128 + chp * 16);
#pragma unroll
      for (int dn = 0; dn < 4; dn++) {
        int dr  = dn * 16 + lr;
        int chv = ((kb << 2) | g) ^ (dr & 7);
        s16x8 vf = *(const s16x8*)((const char*)Vl + dr * 128 + chv * 16);
        o[dn] = MFMA16(pf, vf, o[dn]);
      }
    }
    __syncthreads();
  }

  // normalize + write O as [b, l, h*64+d] bf16
  const int b = bh >> 4, h = bh & 15;
#pragma unroll
  for (int j = 0; j < 4; j++) {
    float inv = 1.0f / lrow[j];
    int lq = q0 + g * 4 + j;
#pragma unroll
    for (int dn = 0; dn < 4; dn++) {
      int d = dn * 16 + lr;
      Ob[((size_t)(b * L_ + lq)) * DIM_ + h * HD_ + d] = f2bf(o[dn][j] * inv);
    }
  }
}

// ---------- launch ----------
extern "C" void kernel_launch(void* const* d_in, const int* in_sizes, int n_in,
                              void* d_out, int out_size, void* d_ws, size_t ws_size,
                              hipStream_t stream) {
  const float* x      = (const float*)d_in[0];   // [4096,1024]
  const float* w_qkv  = (const float*)d_in[1];   // [3072,1024]
  const float* w_proj = (const float*)d_in[2];   // [1024,1024]
  const float* b_proj = (const float*)d_in[3];   // [1024]
  float* out = (float*)d_out;

  const size_t N_X    = (size_t)MTOT * DIM_;     // 4194304
  const size_t N_WQKV = (size_t)3 * DIM_ * DIM_; // 3145728
  const size_t N_WPRJ = (size_t)DIM_ * DIM_;     // 1048576
  const size_t N_QKV  = (size_t)B_ * NH_ * L_ * HD_; // 4194304

  unsigned short* xb     = (unsigned short*)d_ws;
  unsigned short* wqkvb  = xb + N_X;
  unsigned short* wprojb = wqkvb + N_WQKV;
  unsigned short* Qb     = wprojb + N_WPRJ;
  unsigned short* Kb     = Qb + N_QKV;
  unsigned short* Vt     = Kb + N_QKV;
  unsigned short* Obuf   = Vt + N_QKV;
  // total ws use: ~48 MB

  cvt_f32_bf16<<<(int)(N_X / 4 / 256),    256, 0, stream>>>(x,      xb,     (int)(N_X / 4));
  cvt_f32_bf16<<<(int)(N_WQKV / 4 / 256), 256, 0, stream>>>(w_qkv,  wqkvb,  (int)(N_WQKV / 4));
  cvt_f32_bf16<<<(int)(N_WPRJ / 4 / 256), 256, 0, stream>>>(w_proj, wprojb, (int)(N_WPRJ / 4));

  dim3 g1(MTOT / 128, (3 * DIM_) / 128);   // 32 x 24
  gemm_bt<0><<<g1, 256, 0, stream>>>(xb, wqkvb, MTOT, 3 * DIM_, DIM_,
                                     Qb, Kb, Vt, nullptr, nullptr);

  dim3 g2(L_ / 64, B_ * NH_);              // 32 x 32
  attn_fwd<<<g2, 256, 0, stream>>>(Qb, Kb, Vt, Obuf);

  dim3 g3(MTOT / 128, DIM_ / 128);         // 32 x 8
  gemm_bt<1><<<g3, 256, 0, stream>>>(Obuf, wprojb, MTOT, DIM_, DIM_,
                                     nullptr, nullptr, nullptr, out, b_proj);
}

// Round 2
// 171.559 us; speedup vs baseline: 1.1463x; 1.1463x over previous
//
#include <hip/hip_runtime.h>
#include <hip/hip_bf16.h>
#include <stdint.h>
#include <stddef.h>

// ---------- types ----------
typedef short s16x8 __attribute__((ext_vector_type(8)));   // 8 bf16 (bit pattern)
typedef float f32x4  __attribute__((ext_vector_type(4)));
typedef float f32x16 __attribute__((ext_vector_type(16)));

#define MFMA16(a, b, c) __builtin_amdgcn_mfma_f32_16x16x32_bf16((a), (b), (c), 0, 0, 0)
#define MFMA32(a, b, c) __builtin_amdgcn_mfma_f32_32x32x16_bf16((a), (b), (c), 0, 0, 0)

// fp32 -> bf16 (RNE)
__device__ __forceinline__ unsigned short f2bf(float f) {
  union { float f; uint32_t u; } v; v.f = f;
  uint32_t u = v.u;
  return (unsigned short)((u + 0x7FFFu + ((u >> 16) & 1u)) >> 16);
}

__device__ __forceinline__ unsigned int pack_bf16x2(float a, float b) {
  __hip_bfloat162 h = __float22bfloat162_rn(make_float2(a, b));
  union { __hip_bfloat162 h; unsigned int u; } c; c.h = h;
  return c.u;
}

// async global->LDS, 16B per lane. LDS dest must be wave-uniform base + lane*16.
__device__ __forceinline__ void load_lds16(const void* gsrc, void* ldst) {
  void* gp = const_cast<void*>(gsrc);
  __builtin_amdgcn_global_load_lds(
      (__attribute__((address_space(1))) void*)gp,
      (__attribute__((address_space(3))) void*)ldst, 16, 0, 0);
}

// ---------- problem constants ----------
#define B_    2
#define L_    2048
#define DIM_  1024
#define NH_   16
#define HD_   64
#define MTOT  (B_ * L_)       // 4096
// SCALE * log2(e) folded into Q at the QKV-GEMM epilogue -> softmax uses exp2
#define QSCALE_ 0.18033688011112042f

// ---------- fp32 -> bf16 convert (vectorized) ----------
__global__ void cvt_f32_bf16(const float* __restrict__ in, unsigned short* __restrict__ out, int n4) {
  int i = blockIdx.x * blockDim.x + threadIdx.x;
  if (i < n4) {
    float4 v = ((const float4*)in)[i];
    uint2 r;
    r.x = pack_bf16x2(v.x, v.y);
    r.y = pack_bf16x2(v.z, v.w);
    ((uint2*)out)[i] = r;
  }
}

// ---------- GEMM C[m][n] = sum_k A[m][k] * Bw[n][k]  (both bf16, K-major) ----------
// 128x128 tile, BK=32, 4 waves (2x2 of 64x64), 16x16x32 MFMA.
// EPI 0: scatter to Q (pre-scaled) / K  [b,h,l,d] and V^T [b,h,d,l] (bf16).
// EPI 1: fp32 out + bias.
template <int EPI>
__global__ void __launch_bounds__(256)
gemm_bt(const unsigned short* __restrict__ A,
        const unsigned short* __restrict__ Bw,
        int M, int N, int K,
        unsigned short* __restrict__ Qb,
        unsigned short* __restrict__ Kb,
        unsigned short* __restrict__ Vt,
        float* __restrict__ Cout,
        const float* __restrict__ bias) {
  __shared__ __attribute__((aligned(16))) unsigned short Al[128 * 32];
  __shared__ __attribute__((aligned(16))) unsigned short Bl[128 * 32];
  const int tid  = threadIdx.x;
  const int lane = tid & 63, wv = tid >> 6;
  const int g = lane >> 4, lr = lane & 15;
  const int wr = wv >> 1, wc = wv & 1;
  const int m0 = blockIdx.x * 128, n0 = blockIdx.y * 128;

  f32x4 acc[4][4];
  const f32x4 zero = {0.f, 0.f, 0.f, 0.f};
#pragma unroll
  for (int i = 0; i < 4; i++)
#pragma unroll
    for (int j = 0; j < 4; j++) acc[i][j] = zero;

  for (int k0 = 0; k0 < K; k0 += 32) {
#pragma unroll
    for (int pass = 0; pass < 2; ++pass) {
      int c   = pass * 256 + wv * 64 + lane;
      int row = c >> 2, kc = c & 3;
      int ks  = (kc ^ ((row ^ (row >> 2)) & 3)) * 8;
      load_lds16(A  + (size_t)(m0 + row) * K + k0 + ks, (char*)Al + c * 16);
      load_lds16(Bw + (size_t)(n0 + row) * K + k0 + ks, (char*)Bl + c * 16);
    }
    __syncthreads();

    s16x8 af[4], bf[4];
#pragma unroll
    for (int mi = 0; mi < 4; mi++) {
      int row = wr * 64 + mi * 16 + lr;
      int ch  = g ^ ((row ^ (row >> 2)) & 3);
      af[mi]  = *(const s16x8*)((const char*)Al + row * 64 + ch * 16);
    }
#pragma unroll
    for (int ni = 0; ni < 4; ni++) {
      int row = wc * 64 + ni * 16 + lr;
      int ch  = g ^ ((row ^ (row >> 2)) & 3);
      bf[ni]  = *(const s16x8*)((const char*)Bl + row * 64 + ch * 16);
    }
#pragma unroll
    for (int mi = 0; mi < 4; mi++)
#pragma unroll
      for (int ni = 0; ni < 4; ni++)
        acc[mi][ni] = MFMA16(af[mi], bf[ni], acc[mi][ni]);
    __syncthreads();
  }

  if (EPI == 0) {
#pragma unroll
    for (int mi = 0; mi < 4; mi++)
#pragma unroll
      for (int ni = 0; ni < 4; ni++) {
        int ncol = n0 + wc * 64 + ni * 16 + lr;
        int s = ncol >> 10;           // 0=Q 1=K 2=V (uniform per block)
        int h = (ncol >> 6) & 15;
        int d = ncol & 63;
#pragma unroll
        for (int j = 0; j < 4; j++) {
          int m = m0 + wr * 64 + mi * 16 + g * 4 + j;
          int b = m >> 11, l = m & 2047;
          size_t bh = (size_t)(b * NH_ + h);
          if (s == 0)      Qb[(bh * L_ + l) * HD_ + d] = f2bf(acc[mi][ni][j] * QSCALE_);
          else if (s == 1) Kb[(bh * L_ + l) * HD_ + d] = f2bf(acc[mi][ni][j]);
          else             Vt[(bh * HD_ + d) * L_ + l] = f2bf(acc[mi][ni][j]);   // transposed
        }
      }
  } else {
#pragma unroll
    for (int mi = 0; mi < 4; mi++)
#pragma unroll
      for (int ni = 0; ni < 4; ni++) {
        int ncol = n0 + wc * 64 + ni * 16 + lr;
        float bv = bias[ncol];
#pragma unroll
        for (int j = 0; j < 4; j++) {
          int m = m0 + wr * 64 + mi * 16 + g * 4 + j;
          Cout[(size_t)m * N + ncol] = acc[mi][ni][j] + bv;
        }
      }
  }
}

// ---------- flash attention, swapped-QK^T 32x32 structure ----------
// grid: (L/128, B*H). 4 waves x 32 q-rows. KVBLK=64, double-buffered staging.
// Q (pre-scaled): [b,h,l,d]; K: [b,h,l,d]; Vt: [b,h,d,l]; out Ob: [b,l,h*64+d] bf16.
// S^T = mfma32(K, Q): col=q=lane&31 -> each lane owns one q row (32 kv vals; lane^32 has other 32).
__global__ void __launch_bounds__(256)
attn_fwd(const unsigned short* __restrict__ Qb,
         const unsigned short* __restrict__ Kb,
         const unsigned short* __restrict__ Vt,
         unsigned short* __restrict__ Ob) {
  __shared__ __attribute__((aligned(16))) unsigned short Kl[2][64 * 64];   // [kv][d]
  __shared__ __attribute__((aligned(16))) unsigned short Vl[2][64 * 64];   // [d][kv]

  const int tid  = threadIdx.x;
  const int lane = tid & 63, wv = tid >> 6;
  const int hi = lane >> 5, lq = lane & 31;
  const int qt = blockIdx.x, bh = blockIdx.y;

  const unsigned short* Qh = Qb + (size_t)bh * L_ * HD_;
  const unsigned short* Kh = Kb + (size_t)bh * L_ * HD_;
  const unsigned short* Vh = Vt + (size_t)bh * HD_ * L_;
  const int q0 = qt * 128 + wv * 32;

  // Q fragments (B-operand): col=q=lane&31, k = d = ks*16 + hi*8 + e
  s16x8 qf[4];
#pragma unroll
  for (int ks = 0; ks < 4; ++ks)
    qf[ks] = *(const s16x8*)(Qh + (size_t)(q0 + lq) * HD_ + ks * 16 + hi * 8);

  f32x16 o0, o1;
#pragma unroll
  for (int r = 0; r < 16; ++r) { o0[r] = 0.f; o1[r] = 0.f; }
  float rm = -1e30f, rl = 0.f;

  // stage(buf, kv0): K tile [64][64] + V^T tile [64][64], chunk-swizzle ^(row&7)
#define STAGE(buf, kv0)                                                          \
  {                                                                              \
    _Pragma("unroll")                                                            \
    for (int it = 0; it < 2; ++it) {                                             \
      int c = it * 256 + wv * 64 + lane;                                         \
      int row = c >> 3, cc = c & 7;                                              \
      int cs = (cc ^ (row & 7)) * 8;                                             \
      load_lds16(Kh + (size_t)((kv0) + row) * HD_ + cs, (char*)&Kl[buf][0] + c * 16); \
      load_lds16(Vh + (size_t)row * L_ + (kv0) + cs,    (char*)&Vl[buf][0] + c * 16); \
    }                                                                            \
  }

  STAGE(0, 0);
  __syncthreads();

  const int NT = L_ / 64;   // 32
  for (int t = 0; t < NT; ++t) {
    const int cur = t & 1;
    if (t + 1 < NT) STAGE(cur ^ 1, (t + 1) * 64);   // prefetch in flight over compute

    const unsigned short* KL = &Kl[cur][0];
    const unsigned short* VL = &Vl[cur][0];

    // ---- S^T = K * Q  (2 kv-subtiles x 4 k-steps) ----
    f32x16 s0, s1;
#pragma unroll
    for (int r = 0; r < 16; ++r) { s0[r] = 0.f; s1[r] = 0.f; }
    __builtin_amdgcn_s_setprio(1);
#pragma unroll
    for (int ks = 0; ks < 4; ++ks) {
      int cc = ((ks << 1) | hi) ^ (lq & 7);
      s16x8 k0 = *(const s16x8*)((const char*)KL + lq * 128 + cc * 16);
      s0 = MFMA32(k0, qf[ks], s0);
      s16x8 k1 = *(const s16x8*)((const char*)KL + (32 + lq) * 128 + cc * 16);
      s1 = MFMA32(k1, qf[ks], s1);
    }
    __builtin_amdgcn_s_setprio(0);

    // ---- online softmax, in-register (lane owns q=lane&31; lane^32 has other kv half) ----
    f32x16 tm;
#pragma unroll
    for (int r = 0; r < 16; ++r) tm[r] = fmaxf(s0[r], s1[r]);
#pragma unroll
    for (int w = 8; w >= 1; w >>= 1)
#pragma unroll
      for (int r = 0; r < 8; ++r) if (r < w) tm[r] = fmaxf(tm[r], tm[r + w]);
    float pm = fmaxf(tm[0], __shfl_xor(tm[0], 32));
    float mn = fmaxf(rm, pm);
    float al = exp2f(rm - mn);
    rm = mn;
#pragma unroll
    for (int r = 0; r < 16; ++r) { s0[r] = exp2f(s0[r] - mn); s1[r] = exp2f(s1[r] - mn); }
    f32x16 ta;
#pragma unroll
    for (int r = 0; r < 16; ++r) ta[r] = s0[r] + s1[r];
#pragma unroll
    for (int w = 8; w >= 1; w >>= 1)
#pragma unroll
      for (int r = 0; r < 8; ++r) if (r < w) ta[r] += ta[r + w];
    float ps = ta[0] + __shfl_xor(ta[0], 32);
    rl = rl * al + ps;
#pragma unroll
    for (int r = 0; r < 16; ++r) { o0[r] *= al; o1[r] *= al; }

    // ---- pack P^T to bf16 frags + PV:  O^T += V^T * P^T ----
#pragma unroll
    for (int st = 0; st < 2; ++st) {
      unsigned int pd[8];
#pragma unroll
      for (int r2 = 0; r2 < 8; ++r2)
        pd[r2] = st ? pack_bf16x2(s1[2 * r2], s1[2 * r2 + 1])
                    : pack_bf16x2(s0[2 * r2], s0[2 * r2 + 1]);
      // exchange with lane^32: hi=0 needs partner pd{0,1,4,5}; hi=1 needs pd{2,3,6,7}
      unsigned int x[4];
#pragma unroll
      for (int j = 0; j < 4; ++j) {
        int ksl = j >> 1, u = j & 1;
        unsigned int arg = hi ? pd[4 * ksl + u] : pd[4 * ksl + 2 + u];
        x[j] = (unsigned int)__shfl_xor((int)arg, 32);
      }
      __builtin_amdgcn_s_setprio(1);
#pragma unroll
      for (int ksl = 0; ksl < 2; ++ksl) {
        union { unsigned int u[4]; s16x8 v; } pa;
        pa.u[0] = hi ? x[2 * ksl]       : pd[4 * ksl];
        pa.u[1] = hi ? x[2 * ksl + 1]   : pd[4 * ksl + 1];
        pa.u[2] = hi ? pd[4 * ksl + 2]  : x[2 * ksl];
        pa.u[3] = hi ? pd[4 * ksl + 3]  : x[2 * ksl + 1];
#pragma unroll
        for (int dt = 0; dt < 2; ++dt) {
          int row = dt * 32 + lq;
          int cc = (4 * st + 2 * ksl + hi) ^ (row & 7);
          s16x8 vf = *(const s16x8*)((const char*)VL + row * 128 + cc * 16);
          if (dt == 0) o0 = MFMA32(vf, pa.v, o0);
          else         o1 = MFMA32(vf, pa.v, o1);
        }
      }
      __builtin_amdgcn_s_setprio(0);
    }

    __syncthreads();   // drains prefetch vmcnt + protects buffer reuse
  }
#undef STAGE

  // ---- normalize + write O^T: out[b, l=q, h*64+d], paired bf16 stores ----
  const int b = bh >> 4, h = bh & 15;
  const int q = q0 + lq;
  const float inv = 1.0f / rl;
  size_t base = ((size_t)(b * L_ + q)) * DIM_ + h * HD_;
#pragma unroll
  for (int dt = 0; dt < 2; ++dt)
#pragma unroll
    for (int r2 = 0; r2 < 8; ++r2) {
      int d = dt * 32 + 8 * (r2 >> 1) + 4 * hi + 2 * (r2 & 1);
      float a = (dt ? o1[2 * r2] : o0[2 * r2]) * inv;
      float c = (dt ? o1[2 * r2 + 1] : o0[2 * r2 + 1]) * inv;
      unsigned int pv = pack_bf16x2(a, c);
      *(unsigned int*)((unsigned short*)Ob + base + d) = pv;
    }
}

// ---------- launch ----------
extern "C" void kernel_launch(void* const* d_in, const int* in_sizes, int n_in,
                              void* d_out, int out_size, void* d_ws, size_t ws_size,
                              hipStream_t stream) {
  const float* x      = (const float*)d_in[0];   // [4096,1024]
  const float* w_qkv  = (const float*)d_in[1];   // [3072,1024]
  const float* w_proj = (const float*)d_in[2];   // [1024,1024]
  const float* b_proj = (const float*)d_in[3];   // [1024]
  float* out = (float*)d_out;

  const size_t N_X    = (size_t)MTOT * DIM_;
  const size_t N_WQKV = (size_t)3 * DIM_ * DIM_;
  const size_t N_WPRJ = (size_t)DIM_ * DIM_;
  const size_t N_QKV  = (size_t)B_ * NH_ * L_ * HD_;

  unsigned short* xb     = (unsigned short*)d_ws;
  unsigned short* wqkvb  = xb + N_X;
  unsigned short* wprojb = wqkvb + N_WQKV;
  unsigned short* Qb     = wprojb + N_WPRJ;
  unsigned short* Kb     = Qb + N_QKV;
  unsigned short* Vt     = Kb + N_QKV;
  unsigned short* Obuf   = Vt + N_QKV;

  cvt_f32_bf16<<<(int)(N_X / 4 / 256),    256, 0, stream>>>(x,      xb,     (int)(N_X / 4));
  cvt_f32_bf16<<<(int)(N_WQKV / 4 / 256), 256, 0, stream>>>(w_qkv,  wqkvb,  (int)(N_WQKV / 4));
  cvt_f32_bf16<<<(int)(N_WPRJ / 4 / 256), 256, 0, stream>>>(w_proj, wprojb, (int)(N_WPRJ / 4));

  dim3 g1(MTOT / 128, (3 * DIM_) / 128);
  gemm_bt<0><<<g1, 256, 0, stream>>>(xb, wqkvb, MTOT, 3 * DIM_, DIM_,
                                     Qb, Kb, Vt, nullptr, nullptr);

  dim3 g2(L_ / 128, B_ * NH_);             // 16 x 32
  attn_fwd<<<g2, 256, 0, stream>>>(Qb, Kb, Vt, Obuf);

  dim3 g3(MTOT / 128, DIM_ / 128);
  gemm_bt<1><<<g3, 256, 0, stream>>>(Obuf, wprojb, MTOT, DIM_, DIM_,
                                     nullptr, nullptr, nullptr, out, b_proj);
}

// Round 3
// 136.367 us; speedup vs baseline: 1.4421x; 1.2581x over previous
//
#include <hip/hip_runtime.h>
#include <hip/hip_bf16.h>
#include <stdint.h>
#include <stddef.h>

// ---------- types ----------
typedef short s16x8 __attribute__((ext_vector_type(8)));   // 8 bf16 (bit pattern)
typedef float f32x4  __attribute__((ext_vector_type(4)));
typedef float f32x16 __attribute__((ext_vector_type(16)));
typedef unsigned int u32x2 __attribute__((ext_vector_type(2)));

#define MFMA16(a, b, c) __builtin_amdgcn_mfma_f32_16x16x32_bf16((a), (b), (c), 0, 0, 0)
#define MFMA32(a, b, c) __builtin_amdgcn_mfma_f32_32x32x16_bf16((a), (b), (c), 0, 0, 0)
#define EXP2(x) __builtin_amdgcn_exp2f(x)
#define FMAX3(a, b, c) fmaxf(fmaxf((a), (b)), (c))

// fp32 -> bf16 (RNE)
__device__ __forceinline__ unsigned short f2bf(float f) {
  union { float f; uint32_t u; } v; v.f = f;
  uint32_t u = v.u;
  return (unsigned short)((u + 0x7FFFu + ((u >> 16) & 1u)) >> 16);
}

__device__ __forceinline__ unsigned int pack_bf16x2(float a, float b) {
  __hip_bfloat162 h = __float22bfloat162_rn(make_float2(a, b));
  union { __hip_bfloat162 h; unsigned int u; } c; c.h = h;
  return c.u;
}

// async global->LDS, 16B per lane. LDS dest must be wave-uniform base + lane*16.
__device__ __forceinline__ void load_lds16(const void* gsrc, void* ldst) {
  void* gp = const_cast<void*>(gsrc);
  __builtin_amdgcn_global_load_lds(
      (__attribute__((address_space(1))) void*)gp,
      (__attribute__((address_space(3))) void*)ldst, 16, 0, 0);
}

// ---------- problem constants ----------
#define B_    2
#define L_    2048
#define DIM_  1024
#define NH_   16
#define HD_   64
#define MTOT  (B_ * L_)       // 4096
// SCALE * log2(e) folded into Q at the QKV-GEMM epilogue -> softmax uses exp2
#define QSCALE_ 0.18033688011112042f

// ---------- fp32 -> bf16 convert, all 3 tensors in one launch ----------
// float4 units: X4 = 1048576, Q4 = 786432, P4 = 262144  (all %256 == 0)
__global__ void cvt_all(const float* __restrict__ x, const float* __restrict__ wq,
                        const float* __restrict__ wp,
                        unsigned short* __restrict__ xb, unsigned short* __restrict__ wqb,
                        unsigned short* __restrict__ wpb) {
  const int X4 = 1048576, Q4 = 786432;
  int i = blockIdx.x * 256 + threadIdx.x;
  const float* in; unsigned short* out; int idx;
  if (i < X4)            { in = x;  out = xb;  idx = i; }
  else if (i < X4 + Q4)  { in = wq; out = wqb; idx = i - X4; }
  else                   { in = wp; out = wpb; idx = i - X4 - Q4; }
  float4 v = ((const float4*)in)[idx];
  uint2 r;
  r.x = pack_bf16x2(v.x, v.y);
  r.y = pack_bf16x2(v.z, v.w);
  ((uint2*)out)[idx] = r;
}

// ---------- GEMM C[m][n] = sum_k A[m][k] * Bw[n][k]  (both bf16, K-major) ----------
// 128x128 tile, BK=32, 4 waves (2x2 of 64x64), 16x16x32 MFMA, 2-phase prefetch dbuf.
// EPI 0: scatter to Q (pre-scaled) / K  [b,h,l,d] and V^T [b,h,d,l] (bf16).
// EPI 1: fp32 out + bias.
template <int EPI>
__global__ void __launch_bounds__(256)
gemm_bt(const unsigned short* __restrict__ A,
        const unsigned short* __restrict__ Bw,
        int M, int N, int K,
        unsigned short* __restrict__ Qb,
        unsigned short* __restrict__ Kb,
        unsigned short* __restrict__ Vt,
        float* __restrict__ Cout,
        const float* __restrict__ bias) {
  __shared__ __attribute__((aligned(16))) unsigned short Al[2][128 * 32];
  __shared__ __attribute__((aligned(16))) unsigned short Bl[2][128 * 32];
  const int tid  = threadIdx.x;
  const int lane = tid & 63, wv = tid >> 6;
  const int g = lane >> 4, lr = lane & 15;
  const int wr = wv >> 1, wc = wv & 1;
  const int m0 = blockIdx.x * 128, n0 = blockIdx.y * 128;

  f32x4 acc[4][4];
  const f32x4 zero = {0.f, 0.f, 0.f, 0.f};
#pragma unroll
  for (int i = 0; i < 4; i++)
#pragma unroll
    for (int j = 0; j < 4; j++) acc[i][j] = zero;

#define STAGE_G(buf, k0)                                                              \
  {                                                                                   \
    _Pragma("unroll")                                                                 \
    for (int pass = 0; pass < 2; ++pass) {                                            \
      int c   = pass * 256 + wv * 64 + lane;                                          \
      int row = c >> 2, kc = c & 3;                                                   \
      int ks  = (kc ^ ((row ^ (row >> 2)) & 3)) * 8;                                  \
      load_lds16(A  + (size_t)(m0 + row) * K + (k0) + ks, (char*)&Al[buf][0] + c * 16); \
      load_lds16(Bw + (size_t)(n0 + row) * K + (k0) + ks, (char*)&Bl[buf][0] + c * 16); \
    }                                                                                 \
  }

  STAGE_G(0, 0);
  __syncthreads();
  const int NTk = K >> 5;
  for (int t = 0; t < NTk; ++t) {
    const int cur = t & 1;
    if (t + 1 < NTk) STAGE_G(cur ^ 1, (t + 1) * 32);

    s16x8 af[4], bf[4];
#pragma unroll
    for (int mi = 0; mi < 4; mi++) {
      int row = wr * 64 + mi * 16 + lr;
      int ch  = g ^ ((row ^ (row >> 2)) & 3);
      af[mi]  = *(const s16x8*)((const char*)&Al[cur][0] + row * 64 + ch * 16);
    }
#pragma unroll
    for (int ni = 0; ni < 4; ni++) {
      int row = wc * 64 + ni * 16 + lr;
      int ch  = g ^ ((row ^ (row >> 2)) & 3);
      bf[ni]  = *(const s16x8*)((const char*)&Bl[cur][0] + row * 64 + ch * 16);
    }
#pragma unroll
    for (int mi = 0; mi < 4; mi++)
#pragma unroll
      for (int ni = 0; ni < 4; ni++)
        acc[mi][ni] = MFMA16(af[mi], bf[ni], acc[mi][ni]);
    __syncthreads();
  }
#undef STAGE_G

  if (EPI == 0) {
#pragma unroll
    for (int mi = 0; mi < 4; mi++)
#pragma unroll
      for (int ni = 0; ni < 4; ni++) {
        int ncol = n0 + wc * 64 + ni * 16 + lr;
        int s = ncol >> 10;           // 0=Q 1=K 2=V (uniform per block)
        int h = (ncol >> 6) & 15;
        int d = ncol & 63;
#pragma unroll
        for (int j = 0; j < 4; j++) {
          int m = m0 + wr * 64 + mi * 16 + g * 4 + j;
          int b = m >> 11, l = m & 2047;
          size_t bh = (size_t)(b * NH_ + h);
          if (s == 0)      Qb[(bh * L_ + l) * HD_ + d] = f2bf(acc[mi][ni][j] * QSCALE_);
          else if (s == 1) Kb[(bh * L_ + l) * HD_ + d] = f2bf(acc[mi][ni][j]);
          else             Vt[(bh * HD_ + d) * L_ + l] = f2bf(acc[mi][ni][j]);   // transposed
        }
      }
  } else {
#pragma unroll
    for (int mi = 0; mi < 4; mi++)
#pragma unroll
      for (int ni = 0; ni < 4; ni++) {
        int ncol = n0 + wc * 64 + ni * 16 + lr;
        float bv = bias[ncol];
#pragma unroll
        for (int j = 0; j < 4; j++) {
          int m = m0 + wr * 64 + mi * 16 + g * 4 + j;
          Cout[(size_t)m * N + ncol] = acc[mi][ni][j] + bv;
        }
      }
  }
}

// ---------- flash attention, swapped-QK^T 32x32 structure ----------
// grid: (L/128, B*H). 4 waves x 32 q-rows. KVBLK=64, double-buffered staging.
// Q (pre-scaled): [b,h,l,d]; K: [b,h,l,d]; Vt: [b,h,d,l]; out Ob: [b,l,h*64+d] bf16.
// S^T = mfma32(K, Q): col=q=lane&31 -> each lane owns one q row.
// Row-sum via ones-MFMA into o2 (all rows of ones*P equal the full sum).
// Cross-half exchanges via v_permlane32_swap (no LDS, no bank conflicts).
__global__ void __launch_bounds__(256)
attn_fwd(const unsigned short* __restrict__ Qb,
         const unsigned short* __restrict__ Kb,
         const unsigned short* __restrict__ Vt,
         unsigned short* __restrict__ Ob) {
  __shared__ __attribute__((aligned(16))) unsigned short Kl[2][64 * 64];   // [kv][d]
  __shared__ __attribute__((aligned(16))) unsigned short Vl[2][64 * 64];   // [d][kv]

  const int tid  = threadIdx.x;
  const int lane = tid & 63, wv = tid >> 6;
  const int hi = lane >> 5, lq = lane & 31;
  const int qt = blockIdx.x, bh = blockIdx.y;

  const unsigned short* Qh = Qb + (size_t)bh * L_ * HD_;
  const unsigned short* Kh = Kb + (size_t)bh * L_ * HD_;
  const unsigned short* Vh = Vt + (size_t)bh * HD_ * L_;
  const int q0 = qt * 128 + wv * 32;

  // Q fragments (B-operand): col=q=lane&31, k = d = ks*16 + hi*8 + e
  s16x8 qf[4];
#pragma unroll
  for (int ks = 0; ks < 4; ++ks)
    qf[ks] = *(const s16x8*)(Qh + (size_t)(q0 + lq) * HD_ + ks * 16 + hi * 8);

  // ones A-operand fragment (bf16 1.0 = 0x3F80)
  s16x8 onesf;
#pragma unroll
  for (int e = 0; e < 8; ++e) onesf[e] = (short)0x3F80;

  f32x16 o0, o1, o2;
#pragma unroll
  for (int r = 0; r < 16; ++r) { o0[r] = 0.f; o1[r] = 0.f; o2[r] = 0.f; }
  float rm = -1e30f;

#define STAGE(buf, kv0)                                                          \
  {                                                                              \
    _Pragma("unroll")                                                            \
    for (int it = 0; it < 2; ++it) {                                             \
      int c = it * 256 + wv * 64 + lane;                                         \
      int row = c >> 3, cc = c & 7;                                              \
      int cs = (cc ^ (row & 7)) * 8;                                             \
      load_lds16(Kh + (size_t)((kv0) + row) * HD_ + cs, (char*)&Kl[buf][0] + c * 16); \
      load_lds16(Vh + (size_t)row * L_ + (kv0) + cs,    (char*)&Vl[buf][0] + c * 16); \
    }                                                                            \
  }

  STAGE(0, 0);
  __syncthreads();

  const int NT = L_ / 64;   // 32
  for (int t = 0; t < NT; ++t) {
    const int cur = t & 1;
    if (t + 1 < NT) STAGE(cur ^ 1, (t + 1) * 64);   // prefetch in flight over compute

    const unsigned short* KL = &Kl[cur][0];
    const unsigned short* VL = &Vl[cur][0];

    // ---- S^T = K * Q  (2 kv-subtiles x 4 k-steps) ----
    f32x16 s0, s1;
#pragma unroll
    for (int r = 0; r < 16; ++r) { s0[r] = 0.f; s1[r] = 0.f; }
    __builtin_amdgcn_s_setprio(1);
#pragma unroll
    for (int ks = 0; ks < 4; ++ks) {
      int cc = ((ks << 1) | hi) ^ (lq & 7);
      s16x8 k0 = *(const s16x8*)((const char*)KL + lq * 128 + cc * 16);
      s0 = MFMA32(k0, qf[ks], s0);
      s16x8 k1 = *(const s16x8*)((const char*)KL + (32 + lq) * 128 + cc * 16);
      s1 = MFMA32(k1, qf[ks], s1);
    }
    __builtin_amdgcn_s_setprio(0);

    // ---- tile max (per-lane tree + one permlane cross-half) ----
    float t0, t1, t2, t3, t4, t5;
    {
      float m01 = FMAX3(fmaxf(s0[0], s1[0]), fmaxf(s0[1], s1[1]), fmaxf(s0[2], s1[2]));
      float m02 = FMAX3(fmaxf(s0[3], s1[3]), fmaxf(s0[4], s1[4]), fmaxf(s0[5], s1[5]));
      float m03 = FMAX3(fmaxf(s0[6], s1[6]), fmaxf(s0[7], s1[7]), fmaxf(s0[8], s1[8]));
      float m04 = FMAX3(fmaxf(s0[9], s1[9]), fmaxf(s0[10], s1[10]), fmaxf(s0[11], s1[11]));
      float m05 = FMAX3(fmaxf(s0[12], s1[12]), fmaxf(s0[13], s1[13]), fmaxf(s0[14], s1[14]));
      float m06 = fmaxf(s0[15], s1[15]);
      t0 = FMAX3(m01, m02, m03);
      t1 = FMAX3(m04, m05, m06);
    }
    float pmh = fmaxf(t0, t1);
    union { float f; unsigned u; } cu; cu.f = pmh;
    u32x2 sw = __builtin_amdgcn_permlane32_swap(cu.u, cu.u, false, false);
    union { unsigned u; float f; } ca, cb; ca.u = sw[0]; cb.u = sw[1];
    float pm = fmaxf(ca.f, cb.f);

    // ---- defer-max: skip rescale while max grows < 8 (log2 domain) ----
    float mn = rm;
    if (!__all(pm <= rm + 8.0f)) {
      mn = fmaxf(rm, pm);
      float al = EXP2(rm - mn);
#pragma unroll
      for (int r = 0; r < 16; ++r) { o0[r] *= al; o1[r] *= al; }
      o2[0] *= al;
      rm = mn;
    }

    // ---- exp2 (raw v_exp_f32) ----
#pragma unroll
    for (int r = 0; r < 16; ++r) { s0[r] = EXP2(s0[r] - mn); s1[r] = EXP2(s1[r] - mn); }

    // ---- pack P^T to bf16 frags (permlane32_swap exchange) + PV + ones-sum ----
#pragma unroll
    for (int st = 0; st < 2; ++st) {
      unsigned int pd[8];
#pragma unroll
      for (int r2 = 0; r2 < 8; ++r2)
        pd[r2] = st ? pack_bf16x2(s1[2 * r2], s1[2 * r2 + 1])
                    : pack_bf16x2(s0[2 * r2], s0[2 * r2 + 1]);
      __builtin_amdgcn_s_setprio(1);
#pragma unroll
      for (int ksl = 0; ksl < 2; ++ksl) {
        u32x2 e0 = __builtin_amdgcn_permlane32_swap(pd[4 * ksl + 0], pd[4 * ksl + 2], false, false);
        u32x2 e1 = __builtin_amdgcn_permlane32_swap(pd[4 * ksl + 1], pd[4 * ksl + 3], false, false);
        union { unsigned int u[4]; s16x8 v; } pa;
        pa.u[0] = e0[0];   // uniform for both lane halves
        pa.u[1] = e1[0];
        pa.u[2] = e0[1];
        pa.u[3] = e1[1];
#pragma unroll
        for (int dt = 0; dt < 2; ++dt) {
          int row = dt * 32 + lq;
          int cc = (4 * st + 2 * ksl + hi) ^ (row & 7);
          s16x8 vf = *(const s16x8*)((const char*)VL + row * 128 + cc * 16);
          if (dt == 0) o0 = MFMA32(vf, pa.v, o0);
          else         o1 = MFMA32(vf, pa.v, o1);
        }
        o2 = MFMA32(onesf, pa.v, o2);   // row-sum on the matrix pipe
      }
      __builtin_amdgcn_s_setprio(0);
    }

    __syncthreads();   // drains prefetch vmcnt + protects buffer reuse
  }
#undef STAGE

  // ---- normalize + write O^T: out[b, l=q, h*64+d], paired bf16 stores ----
  const int b = bh >> 4, h = bh & 15;
  const int q = q0 + lq;
  const float inv = 1.0f / o2[0];
  size_t base = ((size_t)(b * L_ + q)) * DIM_ + h * HD_;
#pragma unroll
  for (int dt = 0; dt < 2; ++dt)
#pragma unroll
    for (int r2 = 0; r2 < 8; ++r2) {
      int d = dt * 32 + 8 * (r2 >> 1) + 4 * hi + 2 * (r2 & 1);
      float a = (dt ? o1[2 * r2] : o0[2 * r2]) * inv;
      float c = (dt ? o1[2 * r2 + 1] : o0[2 * r2 + 1]) * inv;
      unsigned int pv = pack_bf16x2(a, c);
      *(unsigned int*)((unsigned short*)Ob + base + d) = pv;
    }
}

// ---------- launch ----------
extern "C" void kernel_launch(void* const* d_in, const int* in_sizes, int n_in,
                              void* d_out, int out_size, void* d_ws, size_t ws_size,
                              hipStream_t stream) {
  const float* x      = (const float*)d_in[0];   // [4096,1024]
  const float* w_qkv  = (const float*)d_in[1];   // [3072,1024]
  const float* w_proj = (const float*)d_in[2];   // [1024,1024]
  const float* b_proj = (const float*)d_in[3];   // [1024]
  float* out = (float*)d_out;

  const size_t N_X    = (size_t)MTOT * DIM_;
  const size_t N_WQKV = (size_t)3 * DIM_ * DIM_;
  const size_t N_WPRJ = (size_t)DIM_ * DIM_;
  const size_t N_QKV  = (size_t)B_ * NH_ * L_ * HD_;

  unsigned short* xb     = (unsigned short*)d_ws;
  unsigned short* wqkvb  = xb + N_X;
  unsigned short* wprojb = wqkvb + N_WQKV;
  unsigned short* Qb     = wprojb + N_WPRJ;
  unsigned short* Kb     = Qb + N_QKV;
  unsigned short* Vt     = Kb + N_QKV;
  unsigned short* Obuf   = Vt + N_QKV;

  // one cast launch for all three tensors: (N_X + N_WQKV + N_WPRJ)/4 float4s
  cvt_all<<<8192, 256, 0, stream>>>(x, w_qkv, w_proj, xb, wqkvb, wprojb);

  dim3 g1(MTOT / 128, (3 * DIM_) / 128);
  gemm_bt<0><<<g1, 256, 0, stream>>>(xb, wqkvb, MTOT, 3 * DIM_, DIM_,
                                     Qb, Kb, Vt, nullptr, nullptr);

  dim3 g2(L_ / 128, B_ * NH_);             // 16 x 32
  attn_fwd<<<g2, 256, 0, stream>>>(Qb, Kb, Vt, Obuf);

  dim3 g3(MTOT / 128, DIM_ / 128);
  gemm_bt<1><<<g3, 256, 0, stream>>>(Obuf, wprojb, MTOT, DIM_, DIM_,
                                     nullptr, nullptr, nullptr, out, b_proj);
}